// Round 11
// baseline (924.367 us; speedup 1.0000x reference)
//
#include <hip/hip_runtime.h>
#include <math.h>

typedef unsigned int u32;
typedef unsigned short u16;
typedef unsigned char u8;
typedef unsigned long long u64;
typedef long i64;
typedef i64 i64x2 __attribute__((ext_vector_type(2)));
typedef float f32x4 __attribute__((ext_vector_type(4)));
typedef float f32x16 __attribute__((ext_vector_type(16)));

#define B_  16
#define S_  2048
#define D_  1024
#define H_  256
#define SD_ 14
#define C_  6
#define G_  3
#define E_  18

// hardware fp8 (OCP e4m3 on gfx950) pack: 2 floats -> bytes 0,1 of result
static __device__ __forceinline__ u32 pk8(float a, float b) {
  return (u32)__builtin_amdgcn_cvt_pk_fp8_f32(a, b, 0, false);
}

// ---------------- K3: F f32 -> fp8(x4) + column-mean pooling ----------------
__global__ __launch_bounds__(256) void k_convpool8(const float* __restrict__ F,
                                                   u8* __restrict__ F8,
                                                   float* __restrict__ fsum) {
  const int bb = blockIdx.x >> 5;
  const int sc = blockIdx.x & 31;
  const int t  = threadIdx.x;
  const size_t base = (size_t)(bb * S_ + sc * 64) * D_ + t * 4;
  float s0 = 0.f, s1 = 0.f, s2 = 0.f, s3 = 0.f;
  for (int i = 0; i < 64; ++i) {
    const f32x4 v = *(const f32x4*)(F + base + (size_t)i * D_);
    s0 += v[0]; s1 += v[1]; s2 += v[2]; s3 += v[3];
    const u32 q = pk8(v[0] * 4.f, v[1] * 4.f) | (pk8(v[2] * 4.f, v[3] * 4.f) << 16);
    *(u32*)(F8 + base + (size_t)i * D_) = q;
  }
  const int c = t * 4;
  atomicAdd(&fsum[bb * D_ + c + 0], s0);
  atomicAdd(&fsum[bb * D_ + c + 1], s1);
  atomicAdd(&fsum[bb * D_ + c + 2], s2);
  atomicAdd(&fsum[bb * D_ + c + 3], s3);
}

// ---------------- K3b: pooling only (lean path) ----------------
__global__ __launch_bounds__(256) void k_poolF(const float* __restrict__ F,
                                               float* __restrict__ fsum) {
  const int bb = blockIdx.x >> 5;
  const int sc = blockIdx.x & 31;
  const int t  = threadIdx.x;
  const size_t base = (size_t)(bb * S_ + sc * 64) * D_ + t * 4;
  float s0 = 0.f, s1 = 0.f, s2 = 0.f, s3 = 0.f;
  for (int i = 0; i < 64; ++i) {
    const f32x4 v = *(const f32x4*)(F + base + (size_t)i * D_);
    s0 += v[0]; s1 += v[1]; s2 += v[2]; s3 += v[3];
  }
  const int c = t * 4;
  atomicAdd(&fsum[bb * D_ + c + 0], s0);
  atomicAdd(&fsum[bb * D_ + c + 1], s1);
  atomicAdd(&fsum[bb * D_ + c + 2], s2);
  atomicAdd(&fsum[bb * D_ + c + 3], s3);
}

// ---------------- K1: x_raw column-mean pooling ----------------
__global__ __launch_bounds__(256) void k_xpool(const float* __restrict__ X,
                                               float* __restrict__ xsum) {
  const int b = blockIdx.x;
  const int t = threadIdx.x;
  float ls[SD_];
  #pragma unroll
  for (int c = 0; c < SD_; ++c) ls[c] = 0.f;
  for (int s = t; s < S_; s += 256) {
    const float* row = X + (size_t)(b * S_ + s) * SD_;
    #pragma unroll
    for (int c = 0; c < SD_; ++c) ls[c] += row[c];
  }
  #pragma unroll
  for (int c = 0; c < SD_; ++c) atomicAdd(&xsum[b * SD_ + c], ls[c]);
}

// ---------------- K2: routers + flat weights + expert loads + lb + bias term ----------------
__global__ __launch_bounds__(256) void k_router(const float* __restrict__ fsum,
                                                const float* __restrict__ xsum,
                                                const float* __restrict__ cond_w,
                                                const float* __restrict__ cond_b,
                                                const float* __restrict__ stage_w,
                                                const float* __restrict__ stage_b,
                                                const float* __restrict__ up_b,
                                                float* __restrict__ flatw,
                                                float* __restrict__ biasws,
                                                float* __restrict__ out_tail) {
  __shared__ float s_cl[B_][C_], s_sl[B_][G_];
  __shared__ float s_cw[B_][C_], s_sw[B_][G_];
  __shared__ float s_fw[B_][E_], s_ld[E_];
  const int t = threadIdx.x;
  if (t < B_ * C_) {
    const int b = t / C_, c = t % C_;
    float a = cond_b[c];
    for (int d = 0; d < D_; ++d) a += (fsum[b * D_ + d] * (1.f / S_)) * cond_w[d * C_ + c];
    s_cl[b][c] = a;
  }
  if (t < B_ * G_) {
    const int b = t / G_, g = t % G_;
    float a = stage_b[g];
    for (int sd = 0; sd < SD_; ++sd) a += (xsum[b * SD_ + sd] * (1.f / S_)) * stage_w[sd * G_ + g];
    s_sl[b][g] = a;
  }
  __syncthreads();
  if (t < B_) {
    float m = s_cl[t][0];
    for (int c = 1; c < C_; ++c) m = fmaxf(m, s_cl[t][c]);
    float den = 0.f, ex[C_];
    for (int c = 0; c < C_; ++c) { ex[c] = expf(s_cl[t][c] - m); den += ex[c]; }
    for (int c = 0; c < C_; ++c) s_cw[t][c] = ex[c] / den;
    float m2 = s_sl[t][0];
    for (int g = 1; g < G_; ++g) m2 = fmaxf(m2, s_sl[t][g]);
    float den2 = 0.f, ex2[G_];
    for (int g = 0; g < G_; ++g) { ex2[g] = expf(s_sl[t][g] - m2); den2 += ex2[g]; }
    for (int g = 0; g < G_; ++g) s_sw[t][g] = ex2[g] / den2;
    for (int c = 0; c < C_; ++c)
      for (int g = 0; g < G_; ++g) s_fw[t][c * G_ + g] = s_cw[t][c] * s_sw[t][g];
  }
  __syncthreads();
  if (t < B_ * C_) out_tail[t] = s_cw[t / C_][t % C_];
  if (t < B_ * G_) out_tail[B_ * C_ + t] = s_sw[t / G_][t % G_];
  for (int i = t; i < B_ * E_; i += 256) flatw[i] = s_fw[i / E_][i % E_];
  if (t < E_) {
    float a = 0.f;
    for (int b = 0; b < B_; ++b) a += s_fw[b][t];
    s_ld[t] = a / (float)B_;
    out_tail[B_ * C_ + B_ * G_ + t] = s_ld[t];
  }
  __syncthreads();
  if (t == 0) {
    float a = 0.f;
    for (int e = 0; e < E_; ++e) a += s_ld[e] * s_ld[e];
    out_tail[B_ * C_ + B_ * G_ + E_] = (float)E_ * a * 0.01f;
  }
  for (int i = t; i < B_ * D_; i += 256) {
    const int b = i >> 10, d = i & 1023;
    float a = 0.f;
    #pragma unroll
    for (int e = 0; e < E_; ++e) a += s_fw[b][e] * up_b[e * D_ + d];
    biasws[i] = a;
  }
}

// ---------------- K4: fragmentizer to fp8 for 32x32x16 MFMA ----------------
// src [E][K][N] f32 -> dst frag-linear e4m3 [e][cb=N/32][kb=K/16][lane=64][8B]
// (kb INNERMOST so a wave's sequential kb loads are 512B-contiguous -> imm-offset folding)
//   byte j of lane l = e4m3(src[e][kb*16 + (l>>5)*8 + j][cb*32 + (l&31)] * scale)
__global__ __launch_bounds__(256) void k_frag8(const float* __restrict__ src,
                                               u8* __restrict__ dst, int K, int N,
                                               float scale) {
  const int kgrp = K >> 7;           // 128 k-rows per block
  const int ncb = N >> 5;
  const int bid = blockIdx.x;
  const int kbg = bid % kgrp;
  const int cb  = (bid / kgrp) % ncb;
  const int e   = bid / (kgrp * ncb);
  __shared__ float tile[128][33];
  const int t = threadIdx.x;
  #pragma unroll
  for (int it = 0; it < 16; ++it) {
    const int i = it * 256 + t;
    const int row = i >> 5, col = i & 31;
    tile[row][col] = src[((size_t)e * K + kbg * 128 + row) * N + cb * 32 + col];
  }
  __syncthreads();
  const int lane = t & 63, q = t >> 6;     // q = 0..3
  const int l31 = lane & 31, lhi = lane >> 5;
  #pragma unroll
  for (int h2 = 0; h2 < 2; ++h2) {
    const int kbq = q * 2 + h2;            // 0..7
    const int kb = kbg * 8 + kbq;
    float x[8];
    #pragma unroll
    for (int j = 0; j < 8; ++j) x[j] = tile[kbq * 16 + lhi * 8 + j][l31] * scale;
    const u32 lo = pk8(x[0], x[1]) | (pk8(x[2], x[3]) << 16);
    const u32 hi = pk8(x[4], x[5]) | (pk8(x[6], x[7]) << 16);
    *(u64*)(dst + ((((size_t)e * ncb + cb) * (K >> 4) + kb) * 64 + lane) * 8) =
        (u64)lo | ((u64)hi << 32);
  }
}

#define MFMA32 __builtin_amdgcn_mfma_f32_32x32x16_fp8_fp8

// fast gelu (tanh form via exp2)
static __device__ __forceinline__ float gelu_f(float x) {
  float y2 = 2.302208f * x * (1.f + 0.044715f * x * x);
  y2 = fminf(fmaxf(y2, -30.f), 30.f);
  const float p = __builtin_exp2f(y2);
  return x * p / (p + 1.f);
}

// ---------------- K5: fused MoE main kernel (v11 = v10 + layout micro-opts) ----------------
// Changes vs v10 (MFMA shape & structure identical):
//  1. dwF8/uwF8 kb-innermost -> global loads fold to imm offsets (cuts addr VALU).
//  2. F/Hb LDS unit reorder u' = lhi*half + kstep -> b128 A-reads (2 k-steps per
//     ds_read_b128): down 64->32, up 16->8 LDS reads per wave/expert. Swizzle at
//     16B-granule: granule p XOR (row & mask), bank-uniform.
//  3. up-B prefetch depth 2 pairs (8 loads in flight; pair 0+1 issued pre-barrier).
template<int LEAN>
__global__ __launch_bounds__(512, 2) void k_moe(const u8* __restrict__ F8,
                                                const float* __restrict__ Ff32,
                                                const u8* __restrict__ dwF8,   // [e][8cb][64kb][64][8B]
                                                const u8* __restrict__ uwF8,   // [e][32cb][16kb][64][8B]
                                                const float* __restrict__ down_b,
                                                const float* __restrict__ flatw,
                                                const float* __restrict__ biasws,
                                                float* __restrict__ out) {
  __shared__ u8 Fb[32 * 1024];     // 32 KiB; row=1024B = 64 granules x 16B
  __shared__ u8 Hb[2][32 * 256];   // 2 x 8 KiB; row=256B = 16 granules x 16B

  const int tile = blockIdx.x;
  const int r0 = tile * 32;
  const int b = r0 >> 11;
  const int t = threadIdx.x;
  const int w = t >> 6;
  const int l = t & 63;
  const int l31 = l & 31;
  const int lhi = l >> 5;          // 0..1

  // ---- stage F tile (fp8), unit-reordered + granule-swizzled ----
  // original 8B unit u (=k>>3) -> u' = (u&1)*64 + (u>>1); granule p=u'>>1 XOR (row&31)
  #pragma unroll
  for (int i = 0; i < 8; ++i) {
    const int idx = i * 512 + t;     // 4096 8B-units
    const int row = idx >> 7;        // 0..31
    const int o8  = idx & 127;
    u64 v;
    if constexpr (!LEAN) {
      v = *(const u64*)(F8 + (size_t)(r0 + row) * D_ + o8 * 8);
    } else {
      const float* src = Ff32 + (size_t)(r0 + row) * D_ + o8 * 8;
      const u32 lo = pk8(src[0] * 4.f, src[1] * 4.f) | (pk8(src[2] * 4.f, src[3] * 4.f) << 16);
      const u32 hi = pk8(src[4] * 4.f, src[5] * 4.f) | (pk8(src[6] * 4.f, src[7] * 4.f) << 16);
      v = (u64)lo | ((u64)hi << 32);
    }
    const int up_ = (o8 & 1) * 64 + (o8 >> 1);
    const int adr = row * 1024 + (((((up_ >> 1)) ^ (row & 31)) << 4) | ((up_ & 1) << 3));
    *(u64*)(Fb + adr) = v;
  }

  // down-B base for this wave (cb = w): kb-contiguous, stride 512B
  const u8* dB = dwF8 + (size_t)w * 64 * 512 + l * 8;

  // preload expert-0 down-B, depth 8 (kb=0..7 = one contiguous 4KB run)
  i64 pb[8];
  #pragma unroll
  for (int p = 0; p < 8; ++p)
    pb[p] = *(const i64*)(dB + (size_t)p * 512);

  f32x16 acc[4];
  #pragma unroll
  for (int j = 0; j < 4; ++j)
    #pragma unroll
    for (int i = 0; i < 16; ++i) acc[j][i] = 0.f;

  __syncthreads();

  const float* fwb = flatw + b * E_;

  #pragma unroll 1
  for (int e = 0; e < E_; ++e) {
    u8* hb = Hb[e & 1];
    const u8* dBe = dB + (size_t)e * 8 * 64 * 512;

    // ---- DOWN: h[32 x 32cols/wave] = F(32x1024) @ dw[e], 32 k-pairs ----
    f32x16 hacc0, hacc1;   // even/odd-k chains
    #pragma unroll
    for (int i = 0; i < 16; ++i) { hacc0[i] = 0.f; hacc1[i] = 0.f; }
    i64x2 apair[2];
    apair[0] = *(const i64x2*)(Fb + l31 * 1024 + ((((lhi << 5) + 0) ^ l31) << 4));
    #pragma unroll
    for (int kk2 = 0; kk2 < 32; ++kk2) {
      const int cur = kk2 & 1, nxt = cur ^ 1;
      if (kk2 < 31)
        apair[nxt] = *(const i64x2*)(Fb + l31 * 1024 + ((((lhi << 5) + kk2 + 1) ^ l31) << 4));
      const i64 b0 = pb[(2 * kk2) & 7];
      const i64 b1 = pb[(2 * kk2 + 1) & 7];
      if (kk2 < 28) {
        pb[(2 * kk2) & 7]     = *(const i64*)(dBe + (size_t)(2 * kk2 + 8) * 512);
        pb[(2 * kk2 + 1) & 7] = *(const i64*)(dBe + (size_t)(2 * kk2 + 9) * 512);
      }
      hacc0 = MFMA32(apair[cur][0], b0, hacc0, 0, 0, 0);
      hacc1 = MFMA32(apair[cur][1], b1, hacc1, 0, 0, 0);
    }

    // ---- issue up-B pair0 (ks=0,1) + next-expert pb, then gelu -> Hb[e&1] ----
    const u8* uB0 = uwF8 + ((size_t)e * 32 + w * 4) * 16 * 512 + l * 8;  // fc stride 16*512
    i64 ub[2][2][4];
    #pragma unroll
    for (int fc = 0; fc < 4; ++fc) {
      ub[0][0][fc] = *(const i64*)(uB0 + (size_t)fc * 16 * 512);
      ub[0][1][fc] = *(const i64*)(uB0 + (size_t)fc * 16 * 512 + 512);
    }

    if (e + 1 < E_) {
      const u8* dBn = dB + (size_t)(e + 1) * 8 * 64 * 512;
      #pragma unroll
      for (int p = 0; p < 8; ++p)
        pb[p] = *(const i64*)(dBn + (size_t)p * 512);
    }

    const float wbe = fwb[e];
    {
      const int hc = w * 32 + l31;               // this lane's h-col
      const float dbv = down_b[e * H_ + hc];
      const float sc8 = 8.f * wbe;
      const int u_ = hc >> 3, j_ = hc & 7;
      const int up_ = (u_ & 1) * 16 + (u_ >> 1);
      const int pg_ = up_ >> 1;
      const int lb_ = (up_ & 1) << 3;
      #pragma unroll
      for (int q = 0; q < 4; ++q) {              // reg quads: rows 8q + {0..3} + 4*lhi
        float g[4];
        #pragma unroll
        for (int j = 0; j < 4; ++j) {
          const float x = (hacc0[q * 4 + j] + hacc1[q * 4 + j]) * 0.015625f + dbv;
          g[j] = gelu_f(x) * sc8;
        }
        const u32 p01 = pk8(g[0], g[1]);
        const u32 p23 = pk8(g[2], g[3]);
        #pragma unroll
        for (int j = 0; j < 4; ++j) {
          const int row = 8 * q + j + 4 * lhi;
          const u8 byte = (u8)((j < 2 ? p01 : p23) >> (8 * (j & 1)));
          hb[row * 256 + (((pg_ ^ (row & 15)) << 4) | lb_ | j_)] = byte;
        }
      }
    }

    // single barrier/expert: publishes Hb[e&1]; up(e) reads it while gelu(e+1)
    // writes the OTHER buffer; up(e+1) gated by barrier(e+1).
    __syncthreads();

    // ---- UP: acc[32 x 128cols/wave] += Hb(32x256) @ uw[e], 8 k-pairs ----
    i64x2 ua[2];
    ua[0] = *(const i64x2*)(hb + l31 * 256 + ((((lhi << 3) + 0) ^ (l31 & 15)) << 4));
    #pragma unroll
    for (int ks2 = 0; ks2 < 8; ++ks2) {
      const int cur = ks2 & 1, nxt = cur ^ 1;
      if (ks2 < 7) {
        ua[nxt] = *(const i64x2*)(hb + l31 * 256 + ((((lhi << 3) + ks2 + 1) ^ (l31 & 15)) << 4));
        #pragma unroll
        for (int fc = 0; fc < 4; ++fc) {
          ub[nxt][0][fc] = *(const i64*)(uB0 + (size_t)fc * 16 * 512 + (2 * ks2 + 2) * 512);
          ub[nxt][1][fc] = *(const i64*)(uB0 + (size_t)fc * 16 * 512 + (2 * ks2 + 3) * 512);
        }
      }
      #pragma unroll
      for (int fc = 0; fc < 4; ++fc)
        acc[fc] = MFMA32(ua[cur][0], ub[cur][0][fc], acc[fc], 0, 0, 0);
      #pragma unroll
      for (int fc = 0; fc < 4; ++fc)
        acc[fc] = MFMA32(ua[cur][1], ub[cur][1][fc], acc[fc], 0, 0, 0);
    }
  }

  // ---- epilogue: residual + bias + store; /128 undoes h(x8)*uw(x16) ----
  const float* bias = biasws + b * D_;
  #pragma unroll
  for (int fc = 0; fc < 4; ++fc) {
    const int col = w * 128 + fc * 32 + l31;
    const float bv = bias[col];
    #pragma unroll
    for (int r = 0; r < 16; ++r) {
      const int row = (r & 3) + 8 * (r >> 2) + 4 * lhi;
      const size_t idx = (size_t)(r0 + row) * D_ + col;
      out[idx] = acc[fc][r] * 0.0078125f + Ff32[idx] + bv;
    }
  }
}

extern "C" void kernel_launch(void* const* d_in, const int* in_sizes, int n_in,
                              void* d_out, int out_size, void* d_ws, size_t ws_size,
                              hipStream_t stream) {
  const float* F  = (const float*)d_in[0];
  const float* X  = (const float*)d_in[1];
  const float* dw = (const float*)d_in[2];
  const float* db = (const float*)d_in[3];
  const float* uw = (const float*)d_in[4];
  const float* ub = (const float*)d_in[5];
  const float* cw = (const float*)d_in[6];
  const float* cb = (const float*)d_in[7];
  const float* sw = (const float*)d_in[8];
  const float* sb = (const float*)d_in[9];
  float* out = (float*)d_out;

  char* ws = (char*)d_ws;
  float* fsum  = (float*)ws;                 // B*D
  float* xsum  = fsum + B_ * D_;             // B*SD
  float* flatw = xsum + B_ * SD_;            // B*E
  float* biasws = flatw + B_ * E_;           // B*D
  size_t off = (size_t)(B_ * D_ + B_ * SD_ + B_ * E_ + B_ * D_) * 4;
  off = (off + 255) & ~(size_t)255;
  u8* dwF8 = (u8*)(ws + off); off += (size_t)E_ * H_ * D_;
  u8* uwF8 = (u8*)(ws + off); off += (size_t)E_ * D_ * H_;
  const size_t need_lean = off;
  u8* F8 = (u8*)(ws + off); off += (size_t)B_ * S_ * D_;
  const size_t need_full = off;

  if (ws_size < need_lean) return;
  const bool lean = ws_size < need_full;

  hipMemsetAsync(d_ws, 0, (size_t)(B_ * D_ + B_ * SD_) * sizeof(float), stream);
  // dw [E][D=K][H=N] x16 ; uw [E][H=K][D=N] x16  (32x32x16 frag layout, kb-innermost)
  k_frag8<<<E_ * (D_ / 128) * (H_ / 32), 256, 0, stream>>>(dw, dwF8, D_, H_, 16.f);
  k_frag8<<<E_ * (H_ / 128) * (D_ / 32), 256, 0, stream>>>(uw, uwF8, H_, D_, 16.f);
  if (!lean) {
    k_convpool8<<<512, 256, 0, stream>>>(F, F8, fsum);
  } else {
    k_poolF<<<512, 256, 0, stream>>>(F, fsum);
  }
  k_xpool<<<B_, 256, 0, stream>>>(X, xsum);
  k_router<<<1, 256, 0, stream>>>(fsum, xsum, cw, cb, sw, sb, ub, flatw, biasws,
                                  out + (size_t)B_ * S_ * D_);
  if (!lean) {
    k_moe<0><<<1024, 512, 0, stream>>>(F8, F, dwF8, uwF8, db, flatw, biasws, out);
  } else {
    k_moe<1><<<1024, 512, 0, stream>>>(nullptr, F, dwF8, uwF8, db, flatw, biasws, out);
  }
}